// Round 1
// baseline (1312.680 us; speedup 1.0000x reference)
//
#include <hip/hip_runtime.h>
#include <hip/hip_bf16.h>

#define NUM_B 2
#define SEQ   2048
#define DIM   1024
#define NH    16
#define HD    64
#define M_TOT (NUM_B * SEQ)   // 4096

__device__ __forceinline__ void fma4x4(float acc[4][4], float4 a, float4 b) {
    acc[0][0] += a.x*b.x; acc[0][1] += a.x*b.y; acc[0][2] += a.x*b.z; acc[0][3] += a.x*b.w;
    acc[1][0] += a.y*b.x; acc[1][1] += a.y*b.y; acc[1][2] += a.y*b.z; acc[1][3] += a.y*b.w;
    acc[2][0] += a.z*b.x; acc[2][1] += a.z*b.y; acc[2][2] += a.z*b.z; acc[2][3] += a.z*b.w;
    acc[3][0] += a.w*b.x; acc[3][1] += a.w*b.y; acc[3][2] += a.w*b.z; acc[3][3] += a.w*b.w;
}

// ---------------------------------------------------------------------------
// GEMM1: qkv[m][e] = sum_k x[m][k] * w_qkv[e][k]; scatter into q/k/v [B,H,S,HD]
// BM=BN=64, BK=16, 256 threads, 4x4 micro-tile per thread.
// ---------------------------------------------------------------------------
__global__ __launch_bounds__(256) void gemm_qkv_kernel(
    const float* __restrict__ x, const float* __restrict__ w,
    float* __restrict__ qb, float* __restrict__ kb, float* __restrict__ vb)
{
    __shared__ float As[16][68];   // [k][m], pad 68 keeps float4 alignment + no conflicts
    __shared__ float Bs[16][68];   // [k][n]
    const int t  = threadIdx.x;
    const int tx = t & 15, ty = t >> 4;
    const int lr = t >> 2;           // 0..63 tile row to load
    const int lk = (t & 3) << 2;     // 0,4,8,12 k-offset
    const int m0 = blockIdx.y << 6;
    const int n0 = blockIdx.x << 6;

    float acc[4][4] = {};
    for (int k0 = 0; k0 < DIM; k0 += 16) {
        float4 a = *(const float4*)(x + (size_t)(m0 + lr) * DIM + k0 + lk);
        float4 b = *(const float4*)(w + (size_t)(n0 + lr) * DIM + k0 + lk);
        As[lk+0][lr] = a.x; As[lk+1][lr] = a.y; As[lk+2][lr] = a.z; As[lk+3][lr] = a.w;
        Bs[lk+0][lr] = b.x; Bs[lk+1][lr] = b.y; Bs[lk+2][lr] = b.z; Bs[lk+3][lr] = b.w;
        __syncthreads();
        #pragma unroll
        for (int kk = 0; kk < 16; ++kk) {
            float4 av = *(const float4*)&As[kk][ty << 2];
            float4 bv = *(const float4*)&Bs[kk][tx << 2];
            fma4x4(acc, av, bv);
        }
        __syncthreads();
    }
    // Epilogue: e = n0 + 4*tx + j ; which third -> q/k/v ; head layout [b][h][s][hd]
    const int which = n0 >> 10;             // 0,1,2 (block never crosses a third)
    const int hh    = (n0 & 1023) >> 6;     // head (block never crosses a head: 64-wide)
    float* dst = (which == 0) ? qb : (which == 1) ? kb : vb;
    #pragma unroll
    for (int i = 0; i < 4; ++i) {
        int m  = m0 + (ty << 2) + i;
        int bb = m >> 11;        // / SEQ
        int ss = m & 2047;       // % SEQ
        float4 v4 = make_float4(acc[i][0], acc[i][1], acc[i][2], acc[i][3]);
        *(float4*)(dst + ((size_t)((bb * NH + hh) * SEQ + ss) << 6) + (tx << 2)) = v4;
    }
}

// ---------------------------------------------------------------------------
// GEMM2: out[m][n] = sum_k o[m][k] * w_out[n][k]
// ---------------------------------------------------------------------------
__global__ __launch_bounds__(256) void gemm_out_kernel(
    const float* __restrict__ o, const float* __restrict__ w,
    float* __restrict__ outp)
{
    __shared__ float As[16][68];
    __shared__ float Bs[16][68];
    const int t  = threadIdx.x;
    const int tx = t & 15, ty = t >> 4;
    const int lr = t >> 2;
    const int lk = (t & 3) << 2;
    const int m0 = blockIdx.y << 6;
    const int n0 = blockIdx.x << 6;

    float acc[4][4] = {};
    for (int k0 = 0; k0 < DIM; k0 += 16) {
        float4 a = *(const float4*)(o + (size_t)(m0 + lr) * DIM + k0 + lk);
        float4 b = *(const float4*)(w + (size_t)(n0 + lr) * DIM + k0 + lk);
        As[lk+0][lr] = a.x; As[lk+1][lr] = a.y; As[lk+2][lr] = a.z; As[lk+3][lr] = a.w;
        Bs[lk+0][lr] = b.x; Bs[lk+1][lr] = b.y; Bs[lk+2][lr] = b.z; Bs[lk+3][lr] = b.w;
        __syncthreads();
        #pragma unroll
        for (int kk = 0; kk < 16; ++kk) {
            float4 av = *(const float4*)&As[kk][ty << 2];
            float4 bv = *(const float4*)&Bs[kk][tx << 2];
            fma4x4(acc, av, bv);
        }
        __syncthreads();
    }
    #pragma unroll
    for (int i = 0; i < 4; ++i) {
        int m = m0 + (ty << 2) + i;
        float4 v4 = make_float4(acc[i][0], acc[i][1], acc[i][2], acc[i][3]);
        *(float4*)(outp + (size_t)m * DIM + n0 + (tx << 2)) = v4;
    }
}

// ---------------------------------------------------------------------------
// Flash-style causal attention. One block per (b, h, q-tile of 64 rows).
// Q/K staged transposed [d][row] for float4 fragment reads; V natural [key][d];
// P (post-softmax probs) staged transposed [key][row].
// ---------------------------------------------------------------------------
__global__ __launch_bounds__(256) void attn_kernel(
    const float* __restrict__ qb, const float* __restrict__ kb,
    const float* __restrict__ vb, float* __restrict__ ob)
{
    __shared__ float Qt[64][68];   // [d][r]
    __shared__ float Kt[64][68];   // [d][c]
    __shared__ float Vs[64][68];   // [key][d]
    __shared__ float Pt[64][68];   // [c][r]
    __shared__ float mrow[64], lrow[64], arow[64];

    const int qt = blockIdx.x & 31;       // q-tile (32 per head)
    const int bh = blockIdx.x >> 5;       // 0..31
    const int h  = bh & 15, b = bh >> 4;
    const int t  = threadIdx.x;
    const int tx = t & 15, ty = t >> 4;
    const int q0 = qt << 6;
    const float scale = 0.125f;           // HD^-0.5

    const float* qbase = qb + (size_t)((b * NH + h) * SEQ) * HD;
    const float* kbase = kb + (size_t)((b * NH + h) * SEQ) * HD;
    const float* vbase = vb + (size_t)((b * NH + h) * SEQ) * HD;

    // Load Q tile transposed
    #pragma unroll
    for (int c = 0; c < 4; ++c) {
        int e = (t + c * 256) << 2;
        int r = e >> 6;
        int d = e & 63;
        float4 qv = *(const float4*)(qbase + (size_t)(q0 + r) * HD + d);
        Qt[d+0][r] = qv.x; Qt[d+1][r] = qv.y; Qt[d+2][r] = qv.z; Qt[d+3][r] = qv.w;
    }
    if (t < 64) { mrow[t] = -1e30f; lrow[t] = 0.f; }
    float acc[4][4] = {};
    __syncthreads();

    for (int kt = 0; kt <= qt; ++kt) {
        const int j0 = kt << 6;
        // Load K (transposed) and V (natural) tiles
        #pragma unroll
        for (int c = 0; c < 4; ++c) {
            int e = (t + c * 256) << 2;
            int r = e >> 6;
            int d = e & 63;
            float4 kv = *(const float4*)(kbase + (size_t)(j0 + r) * HD + d);
            Kt[d+0][r] = kv.x; Kt[d+1][r] = kv.y; Kt[d+2][r] = kv.z; Kt[d+3][r] = kv.w;
            float4 vv = *(const float4*)(vbase + (size_t)(j0 + r) * HD + d);
            *(float4*)&Vs[r][d] = vv;
        }
        __syncthreads();

        // Scores S = Q K^T (4x4 per thread over 64-dim reduction)
        float sc[4][4] = {};
        #pragma unroll 8
        for (int d = 0; d < HD; ++d) {
            float4 qv = *(const float4*)&Qt[d][ty << 2];
            float4 kv = *(const float4*)&Kt[d][tx << 2];
            fma4x4(sc, qv, kv);
        }
        // scale + causal mask, write transposed P-staging Pt[c][r]
        const bool diag = (kt == qt);
        const int r0 = q0 + (ty << 2);
        #pragma unroll
        for (int j = 0; j < 4; ++j) {
            int cg = j0 + (tx << 2) + j;
            float p0 = sc[0][j] * scale;
            float p1 = sc[1][j] * scale;
            float p2 = sc[2][j] * scale;
            float p3 = sc[3][j] * scale;
            if (diag) {
                if (cg > r0 + 0) p0 = -1e30f;
                if (cg > r0 + 1) p1 = -1e30f;
                if (cg > r0 + 2) p2 = -1e30f;
                if (cg > r0 + 3) p3 = -1e30f;
            }
            *(float4*)&Pt[(tx << 2) + j][ty << 2] = make_float4(p0, p1, p2, p3);
        }
        __syncthreads();

        // Online softmax: one thread per row (wave 0)
        if (t < 64) {
            float mold = mrow[t];
            float mx = mold;
            #pragma unroll 16
            for (int c2 = 0; c2 < 64; ++c2) mx = fmaxf(mx, Pt[c2][t]);
            float al = __expf(mold - mx);
            float sum = 0.f;
            #pragma unroll 16
            for (int c2 = 0; c2 < 64; ++c2) {
                float p = __expf(Pt[c2][t] - mx);
                Pt[c2][t] = p;
                sum += p;
            }
            mrow[t] = mx;
            arow[t] = al;
            lrow[t] = lrow[t] * al + sum;
        }
        __syncthreads();

        // O = alpha*O + P V
        float al0 = arow[(ty << 2) + 0];
        float al1 = arow[(ty << 2) + 1];
        float al2 = arow[(ty << 2) + 2];
        float al3 = arow[(ty << 2) + 3];
        #pragma unroll
        for (int j = 0; j < 4; ++j) {
            acc[0][j] *= al0; acc[1][j] *= al1; acc[2][j] *= al2; acc[3][j] *= al3;
        }
        #pragma unroll 8
        for (int kk = 0; kk < 64; ++kk) {
            float4 pv = *(const float4*)&Pt[kk][ty << 2];
            float4 vv = *(const float4*)&Vs[kk][tx << 2];
            fma4x4(acc, pv, vv);
        }
        __syncthreads();   // protect Kt/Vs/Pt before next tile's loads
    }

    // Epilogue: normalize by l, write o in [B,S,D] layout for the out-proj GEMM
    #pragma unroll
    for (int i = 0; i < 4; ++i) {
        int r = (ty << 2) + i;
        float inv = 1.0f / lrow[r];
        float4 o4 = make_float4(acc[i][0] * inv, acc[i][1] * inv,
                                acc[i][2] * inv, acc[i][3] * inv);
        *(float4*)(ob + (size_t)(b * SEQ + q0 + r) * DIM + h * HD + (tx << 2)) = o4;
    }
}

extern "C" void kernel_launch(void* const* d_in, const int* in_sizes, int n_in,
                              void* d_out, int out_size, void* d_ws, size_t ws_size,
                              hipStream_t stream) {
    const float* x     = (const float*)d_in[0];   // [B,S,D]
    const float* w_qkv = (const float*)d_in[1];   // [3D,D]
    const float* w_out = (const float*)d_in[2];   // [D,D]
    float* out = (float*)d_out;                   // [B,S,D]
    float* ws  = (float*)d_ws;

    const size_t HEADSZ = (size_t)NUM_B * NH * SEQ * HD;  // 4,194,304 floats
    float* qb = ws;
    float* kb = ws + HEADSZ;
    float* vb = ws + 2 * HEADSZ;
    float* ob = ws + 3 * HEADSZ;                          // [B,S,D]

    dim3 g1((3 * DIM) / 64, M_TOT / 64);   // 48 x 64
    gemm_qkv_kernel<<<g1, 256, 0, stream>>>(x, w_qkv, qb, kb, vb);

    attn_kernel<<<NUM_B * NH * (SEQ / 64), 256, 0, stream>>>(qb, kb, vb, ob);

    dim3 g2(DIM / 64, M_TOT / 64);         // 16 x 64
    gemm_out_kernel<<<g2, 256, 0, stream>>>(ob, w_out, out);
}

// Round 2
// 234.576 us; speedup vs baseline: 5.5960x; 5.5960x over previous
//
#include <hip/hip_runtime.h>

#define NUM_B 2
#define SEQ   2048
#define DIM   1024
#define NH    16
#define HD    64

typedef __attribute__((ext_vector_type(8))) short short8;
typedef __attribute__((ext_vector_type(4))) float floatx4;

__device__ __forceinline__ unsigned short f2bf(float f) {
    unsigned u = __float_as_uint(f);
    u += 0x7fffu + ((u >> 16) & 1u);
    return (unsigned short)(u >> 16);
}

// ---------------------------------------------------------------------------
// fp32 -> bf16 cast, 8 elements/thread
// ---------------------------------------------------------------------------
__global__ __launch_bounds__(256) void cast_kernel(const float* __restrict__ in,
                                                   unsigned short* __restrict__ out,
                                                   int n8) {
    int i = blockIdx.x * 256 + threadIdx.x;
    if (i >= n8) return;
    const float4* p = (const float4*)in + (size_t)i * 2;
    float4 f0 = p[0];
    float4 f1 = p[1];
    short8 v;
    v[0] = (short)f2bf(f0.x); v[1] = (short)f2bf(f0.y);
    v[2] = (short)f2bf(f0.z); v[3] = (short)f2bf(f0.w);
    v[4] = (short)f2bf(f1.x); v[5] = (short)f2bf(f1.y);
    v[6] = (short)f2bf(f1.z); v[7] = (short)f2bf(f1.w);
    *(short8*)(out + (size_t)i * 8) = v;
}

// ---------------------------------------------------------------------------
// GEMM1: qkv[m][e] = sum_k x[m][k]*w_qkv[e][k]  (both K-contiguous, NT)
// 128x128 tile, BK=32, 256 thr = 4 waves, wave = 64x64 (4x4 MFMA 16x16x32).
// Epilogue scatters q,k -> [b,h,s,hd] bf16 ; v -> TRANSPOSED [b,h,hd,s] bf16.
// ---------------------------------------------------------------------------
__global__ __launch_bounds__(256, 2) void gemm_qkv(
    const unsigned short* __restrict__ A, const unsigned short* __restrict__ Bw,
    unsigned short* __restrict__ qb, unsigned short* __restrict__ kb,
    unsigned short* __restrict__ vt)
{
    __shared__ unsigned short As[128 * 32];
    __shared__ unsigned short Bs[128 * 32];
    const int t = threadIdx.x;
    const int lane = t & 63, w = t >> 6;
    const int l16 = lane & 15, quad = lane >> 4;
    const int wr = (w >> 1) * 64, wc = (w & 1) * 64;
    const int m0 = blockIdx.y * 128, n0 = blockIdx.x * 128;

    floatx4 acc[4][4];
    #pragma unroll
    for (int i = 0; i < 4; ++i)
        #pragma unroll
        for (int j = 0; j < 4; ++j) acc[i][j] = (floatx4){0.f, 0.f, 0.f, 0.f};

    for (int k0 = 0; k0 < DIM; k0 += 32) {
        #pragma unroll
        for (int c = 0; c < 2; ++c) {
            int f = c * 256 + t;
            int row = f >> 2, k8 = (f & 3) << 3;
            *(float4*)&As[row * 32 + k8] = *(const float4*)(A  + (size_t)(m0 + row) * DIM + k0 + k8);
            *(float4*)&Bs[row * 32 + k8] = *(const float4*)(Bw + (size_t)(n0 + row) * DIM + k0 + k8);
        }
        __syncthreads();
        short8 af[4], bf[4];
        #pragma unroll
        for (int i = 0; i < 4; ++i) af[i] = *(const short8*)&As[(wr + i * 16 + l16) * 32 + quad * 8];
        #pragma unroll
        for (int j = 0; j < 4; ++j) bf[j] = *(const short8*)&Bs[(wc + j * 16 + l16) * 32 + quad * 8];
        #pragma unroll
        for (int i = 0; i < 4; ++i)
            #pragma unroll
            for (int j = 0; j < 4; ++j)
                acc[i][j] = __builtin_amdgcn_mfma_f32_16x16x32_bf16(af[i], bf[j], acc[i][j], 0, 0, 0);
        __syncthreads();
    }

    #pragma unroll
    for (int i = 0; i < 4; ++i) {
        #pragma unroll
        for (int j = 0; j < 4; ++j) {
            int e = n0 + wc + j * 16 + l16;
            int which = e >> 10;
            int h  = (e >> 6) & 15;
            int hd = e & 63;
            #pragma unroll
            for (int r = 0; r < 4; ++r) {
                int m = m0 + wr + i * 16 + quad * 4 + r;
                int b = m >> 11, s = m & 2047;
                unsigned short v = f2bf(acc[i][j][r]);
                if (which == 0)      qb[((size_t)((b * NH + h) * SEQ + s) << 6) + hd] = v;
                else if (which == 1) kb[((size_t)((b * NH + h) * SEQ + s) << 6) + hd] = v;
                else                 vt[((size_t)((b * NH + h) * HD + hd) << 11) + s] = v;
            }
        }
    }
}

// ---------------------------------------------------------------------------
// GEMM2: out[m][n] = sum_k o[m][k]*w_out[n][k], fp32 output
// ---------------------------------------------------------------------------
__global__ __launch_bounds__(256, 2) void gemm_out(
    const unsigned short* __restrict__ A, const unsigned short* __restrict__ Bw,
    float* __restrict__ outp)
{
    __shared__ unsigned short As[128 * 32];
    __shared__ unsigned short Bs[128 * 32];
    const int t = threadIdx.x;
    const int lane = t & 63, w = t >> 6;
    const int l16 = lane & 15, quad = lane >> 4;
    const int wr = (w >> 1) * 64, wc = (w & 1) * 64;
    const int m0 = blockIdx.y * 128, n0 = blockIdx.x * 128;

    floatx4 acc[4][4];
    #pragma unroll
    for (int i = 0; i < 4; ++i)
        #pragma unroll
        for (int j = 0; j < 4; ++j) acc[i][j] = (floatx4){0.f, 0.f, 0.f, 0.f};

    for (int k0 = 0; k0 < DIM; k0 += 32) {
        #pragma unroll
        for (int c = 0; c < 2; ++c) {
            int f = c * 256 + t;
            int row = f >> 2, k8 = (f & 3) << 3;
            *(float4*)&As[row * 32 + k8] = *(const float4*)(A  + (size_t)(m0 + row) * DIM + k0 + k8);
            *(float4*)&Bs[row * 32 + k8] = *(const float4*)(Bw + (size_t)(n0 + row) * DIM + k0 + k8);
        }
        __syncthreads();
        short8 af[4], bf[4];
        #pragma unroll
        for (int i = 0; i < 4; ++i) af[i] = *(const short8*)&As[(wr + i * 16 + l16) * 32 + quad * 8];
        #pragma unroll
        for (int j = 0; j < 4; ++j) bf[j] = *(const short8*)&Bs[(wc + j * 16 + l16) * 32 + quad * 8];
        #pragma unroll
        for (int i = 0; i < 4; ++i)
            #pragma unroll
            for (int j = 0; j < 4; ++j)
                acc[i][j] = __builtin_amdgcn_mfma_f32_16x16x32_bf16(af[i], bf[j], acc[i][j], 0, 0, 0);
        __syncthreads();
    }

    #pragma unroll
    for (int i = 0; i < 4; ++i)
        #pragma unroll
        for (int j = 0; j < 4; ++j) {
            int n = n0 + wc + j * 16 + l16;
            #pragma unroll
            for (int r = 0; r < 4; ++r) {
                int m = m0 + wr + i * 16 + quad * 4 + r;
                outp[(size_t)m * DIM + n] = acc[i][j][r];
            }
        }
}

// ---------------------------------------------------------------------------
// MFMA flash attention (bf16). Block = 256 thr = 4 waves; each wave owns 16
// q-rows (Q-frags register-resident). Work-balanced: block processes q-tiles
// pidx and 31-pidx (uniform 33 k-tiles). Softmax in registers via shfl_xor.
// P goes C-layout -> LDS (stride 72) -> A-layout frags for PV.
// ---------------------------------------------------------------------------
__global__ __launch_bounds__(256, 2) void attn(
    const unsigned short* __restrict__ qb, const unsigned short* __restrict__ kb,
    const unsigned short* __restrict__ vt, unsigned short* __restrict__ ob)
{
    __shared__ unsigned short Ks[64 * 64];
    __shared__ unsigned short Vs[64 * 64];     // transposed: [d][key]
    __shared__ unsigned short Ps[4 * 16 * 72];
    const int t = threadIdx.x;
    const int lane = t & 63, w = t >> 6;
    const int l16 = lane & 15, quad = lane >> 4;
    const int pidx = blockIdx.x & 15;
    const int bh = blockIdx.x >> 4;            // 0..31
    const int b = bh >> 4, h = bh & 15;
    const size_t base = (size_t)bh * SEQ * HD;
    const unsigned short* qbh = qb + base;
    const unsigned short* kbh = kb + base;
    const unsigned short* vth = vt + base;     // [64][2048]
    unsigned short* Pp = Ps + w * 16 * 72;

    for (int half = 0; half < 2; ++half) {
        const int qt = half ? (31 - pidx) : pidx;
        const int q0 = qt * 64;
        const int rowb = q0 + w * 16 + quad * 4;   // +r = global q row

        short8 qa[2];
        #pragma unroll
        for (int s = 0; s < 2; ++s)
            qa[s] = *(const short8*)(qbh + (size_t)(q0 + w * 16 + l16) * HD + s * 32 + quad * 8);

        floatx4 o[4];
        #pragma unroll
        for (int j = 0; j < 4; ++j) o[j] = (floatx4){0.f, 0.f, 0.f, 0.f};
        float mrow[4] = {-1e30f, -1e30f, -1e30f, -1e30f};
        float lrow[4] = {0.f, 0.f, 0.f, 0.f};

        for (int kt = 0; kt <= qt; ++kt) {
            const int j0 = kt * 64;
            #pragma unroll
            for (int c = 0; c < 2; ++c) {
                int f = c * 256 + t;
                int row = f >> 3, off8 = (f & 7) << 3;
                *(float4*)&Ks[row * 64 + off8] = *(const float4*)(kbh + (size_t)(j0 + row) * HD + off8);
                *(float4*)&Vs[row * 64 + off8] = *(const float4*)(vth + (size_t)row * SEQ + j0 + off8);
            }
            __syncthreads();

            floatx4 sf[4];
            #pragma unroll
            for (int j = 0; j < 4; ++j) sf[j] = (floatx4){0.f, 0.f, 0.f, 0.f};
            #pragma unroll
            for (int s = 0; s < 2; ++s)
                #pragma unroll
                for (int j = 0; j < 4; ++j) {
                    short8 kf = *(const short8*)&Ks[(j * 16 + l16) * 64 + s * 32 + quad * 8];
                    sf[j] = __builtin_amdgcn_mfma_f32_16x16x32_bf16(qa[s], kf, sf[j], 0, 0, 0);
                }

            float p[4][4];
            const bool diag = (kt == qt);
            #pragma unroll
            for (int j = 0; j < 4; ++j) {
                int colg = j0 + j * 16 + l16;
                #pragma unroll
                for (int r = 0; r < 4; ++r) {
                    float v = sf[j][r] * 0.125f;
                    if (diag && colg > rowb + r) v = -1e30f;
                    p[j][r] = v;
                }
            }
            #pragma unroll
            for (int r = 0; r < 4; ++r) {
                float mx = fmaxf(fmaxf(p[0][r], p[1][r]), fmaxf(p[2][r], p[3][r]));
                mx = fmaxf(mx, __shfl_xor(mx, 1));
                mx = fmaxf(mx, __shfl_xor(mx, 2));
                mx = fmaxf(mx, __shfl_xor(mx, 4));
                mx = fmaxf(mx, __shfl_xor(mx, 8));
                float mnew = fmaxf(mrow[r], mx);
                float al = __expf(mrow[r] - mnew);
                mrow[r] = mnew;
                float sum = 0.f;
                #pragma unroll
                for (int j = 0; j < 4; ++j) { p[j][r] = __expf(p[j][r] - mnew); sum += p[j][r]; }
                sum += __shfl_xor(sum, 1);
                sum += __shfl_xor(sum, 2);
                sum += __shfl_xor(sum, 4);
                sum += __shfl_xor(sum, 8);
                lrow[r] = lrow[r] * al + sum;
                #pragma unroll
                for (int j = 0; j < 4; ++j) o[j][r] *= al;
            }
            #pragma unroll
            for (int j = 0; j < 4; ++j)
                #pragma unroll
                for (int r = 0; r < 4; ++r)
                    Pp[(quad * 4 + r) * 72 + j * 16 + l16] = f2bf(p[j][r]);
            #pragma unroll
            for (int s = 0; s < 2; ++s) {
                short8 pf = *(const short8*)&Pp[l16 * 72 + s * 32 + quad * 8];
                #pragma unroll
                for (int j = 0; j < 4; ++j) {
                    short8 vf = *(const short8*)&Vs[(j * 16 + l16) * 64 + s * 32 + quad * 8];
                    o[j] = __builtin_amdgcn_mfma_f32_16x16x32_bf16(pf, vf, o[j], 0, 0, 0);
                }
            }
            __syncthreads();
        }

        #pragma unroll
        for (int j = 0; j < 4; ++j)
            #pragma unroll
            for (int r = 0; r < 4; ++r) {
                float val = o[j][r] / lrow[r];
                ob[(size_t)(b * SEQ + rowb + r) * DIM + h * HD + j * 16 + l16] = f2bf(val);
            }
    }
}

extern "C" void kernel_launch(void* const* d_in, const int* in_sizes, int n_in,
                              void* d_out, int out_size, void* d_ws, size_t ws_size,
                              hipStream_t stream) {
    const float* x     = (const float*)d_in[0];   // [B,S,D]
    const float* w_qkv = (const float*)d_in[1];   // [3D,D]
    const float* w_out = (const float*)d_in[2];   // [D,D]
    float* out = (float*)d_out;
    unsigned short* ws = (unsigned short*)d_ws;

    const size_t M1 = (size_t)1024 * 1024;
    unsigned short* xb  = ws;             // 4M shorts
    unsigned short* wqb = xb  + 4 * M1;   // 3M
    unsigned short* wob = wqb + 3 * M1;   // 1M
    unsigned short* qb  = wob + 1 * M1;   // 4M
    unsigned short* kb  = qb  + 4 * M1;   // 4M
    unsigned short* vt  = kb  + 4 * M1;   // 4M (transposed [b,h,d,s])
    unsigned short* obf = vt  + 4 * M1;   // 4M  -> 24M shorts = 48 MB total

    cast_kernel<<<2048, 256, 0, stream>>>(x, xb, 524288);
    cast_kernel<<<1536, 256, 0, stream>>>(w_qkv, wqb, 393216);
    cast_kernel<<<512,  256, 0, stream>>>(w_out, wob, 131072);

    gemm_qkv<<<dim3(24, 32), 256, 0, stream>>>(xb, wqb, qb, kb, vt);
    attn<<<512, 256, 0, stream>>>(qb, kb, vt, obf);
    gemm_out<<<dim3(8, 32), 256, 0, stream>>>(obf, wob, out);
}